// Round 11
// baseline (101.357 us; speedup 1.0000x reference)
//
#include <hip/hip_runtime.h>
#include <math.h>

// Problem constants
#define NB    256           // N nodes
#define EDIM  16            // edge MLP hidden
#define FINN  32            // Fin
#define FOUTN 32            // Fout
#define BT    128           // B*T
#define KKD   4096          // GEMM K index: e*256 + j

typedef __attribute__((ext_vector_type(8))) short short8;   // 8 bf16 = 4 VGPRs
typedef __attribute__((ext_vector_type(4))) float floatx4;  // MFMA accumulator

#define MFMA16(a,b,c) __builtin_amdgcn_mfma_f32_16x16x32_bf16((a),(b),(c),0,0,0)

// LDS-only barrier (no vmcnt(0) drain of in-flight global register loads).
#define BARRIER() asm volatile("s_waitcnt lgkmcnt(0)\n\ts_barrier" ::: "memory")

__device__ __forceinline__ float gelu_f(float v) {
    return 0.5f * v * (1.0f + erff(v * 0.70710678118654752f));
}
__device__ __forceinline__ ushort f2bf(float x) {
    union { float f; unsigned u; } v; v.f = x;
    unsigned r = (v.u + 0x7FFFu + ((v.u >> 16) & 1u)) >> 16;
    return (ushort)r;
}
__device__ __forceinline__ float bf2f(ushort b) {
    union { unsigned u; float f; } v; v.u = ((unsigned)b) << 16; return v.f;
}

// ---------------------------------------------------------------------------
// Prep: blocks [0,128): H in MFMA A-fragment order.
//       block 128:      w2 -> bf16 in MFMA B-fragment order.
// ---------------------------------------------------------------------------
__global__ __launch_bounds__(256) void h_kernel(const float* __restrict__ adj,
                                                const float* __restrict__ w1,
                                                const float* __restrict__ b1,
                                                const float* __restrict__ w2,
                                                ushort* __restrict__ Hf,
                                                ushort* __restrict__ w2f) {
    int tid = threadIdx.x;
    if (blockIdx.x >= 128) {
        for (int s = 0; s < 2048; s += 256) {
            int slot = s + tid;             // (e*2+ot)*64 + lane
            int e = slot >> 7, r = slot & 127;
            int ot = r >> 6, lane = r & 63;
            int m = lane & 15, quad = lane >> 4;
            const float* src = w2 + (size_t)e * 1024 + (quad * 8) * 32 + ot * 16 + m;
            ushort tmp[8];
            #pragma unroll
            for (int i = 0; i < 8; ++i) tmp[i] = f2bf(src[i * 32]);
            *(int4*)(w2f + (size_t)slot * 8) = *(int4*)tmp;
        }
        return;
    }
    __shared__ float adjs[16][264];
    __shared__ float w1s[16], b1s[16];
    int it = blockIdx.x & 15;
    int kq = blockIdx.x >> 4;               // 0..7
    if (tid < 16) { w1s[tid] = w1[tid]; b1s[tid] = b1[tid]; }
    #pragma unroll
    for (int q = 0; q < 4; ++q) {
        int u = q * 256 + tid;
        int row = u >> 6, c4 = u & 63;
        *(float4*)&adjs[row][c4 * 4] =
            ((const float4*)(adj + ((size_t)it * 16 + row) * 256))[c4];
    }
    __syncthreads();
    #pragma unroll
    for (int q = 0; q < 4; ++q) {
        int u = q * 256 + tid;              // 16 ks x 64 lanes
        int ks = kq * 16 + (u >> 6);
        int lane = u & 63;
        int m = lane & 15, quad = lane >> 4;
        int e = ks >> 3;
        int j0 = (ks & 7) * 32 + quad * 8;
        float w = w1s[e], b = b1s[e];
        ushort tmp[8];
        #pragma unroll
        for (int d = 0; d < 8; ++d)
            tmp[d] = f2bf(gelu_f(adjs[m][j0 + d] * w + b));
        *(int4*)(Hf + (((size_t)it * 128 + ks) * 64 + lane) * 8) = *(int4*)tmp;
    }
}

// ---------------------------------------------------------------------------
// Fused y2 + GEMM + epilogue, bt-PAIRED: block = (bt-pair, iq); grid (64,4);
// 256 thr = 4 waves; LDS ~114 KB -> 1 block/CU. Each A-fragment load from
// Hf (L2) now feeds GEMMs for TWO bt -> total H re-read traffic halved
// (256 MB -> 128 MB), attacking the invariant that R8/R9/R10 never changed.
// Window c: ALOAD(c)+WLOADB(c+1) fired first (consumed next window, never
// drained at barriers); PRODUCE(c) for both bt; GEMM(c-1) for both bt;
// raw lgkmcnt barrier.
// ---------------------------------------------------------------------------
#define NCH  16
#define BSP  264   // Bs padded row (bf16)
#define XBP  40    // xb/nwT padded row (bf16)

__global__ __launch_bounds__(256, 1) void fused_kernel(
        const float* __restrict__ x,      const ushort* __restrict__ w2f,
        const float* __restrict__ b2,     const float* __restrict__ node_w,
        const float* __restrict__ node_b, const ushort* __restrict__ Hf,
        float* __restrict__ out) {
    __shared__ ushort xb[2][NB][XBP];      // 40 KiB   x[bt0..bt1] in bf16
    __shared__ ushort Bs[2][2][32][BSP];   // 66 KiB   [bt][dbuf][o][j]
    __shared__ ushort nwT[32][XBP];        // 2.5 KiB  node_w^T in bf16
    __shared__ float  Sp[2][8][32];
    __shared__ float  Sv[2][32];
    __shared__ float  bias2[2][32];

    int pr   = blockIdx.x;              // 0..63  -> bt {2pr, 2pr+1}
    int iq   = blockIdx.y;              // 0..3
    int tid  = threadIdx.x;
    int wv   = tid >> 6;                // 0..3
    int lane = tid & 63;
    int m    = lane & 15;
    int quad = lane >> 4;
    int it   = iq * 4 + wv;             // wave's i-tile (16 rows)
    int i0g  = it * 16;
    int bt0  = pr * 2;

    const ushort* Hlane = Hf + (size_t)it * 128 * 512 + lane * 8;
    const ushort* Wlane = w2f + (size_t)lane * 8;

    short8 areg[2][8];                  // A-frag ping-pong (shared by both bt)
    short8 wreg[2][2];                  // w2-frag ping-pong (both o-halves)

    #define ALOAD(dst, c)                                                     \
    {                                                                         \
        _Pragma("unroll")                                                     \
        for (int kk = 0; kk < 8; ++kk)                                        \
            dst[kk] = *(const short8*)(Hlane + ((c) * 8 + kk) * 512);         \
    }
    #define WLOADB(dst, e)                                                    \
    {                                                                         \
        dst[0] = *(const short8*)(Wlane + (size_t)(e) * 1024);                \
        dst[1] = *(const short8*)(Wlane + (size_t)(e) * 1024 + 512);          \
    }

    WLOADB(wreg[0], 0);                 // chunk-0 w2 frags (used after staging)

    // ---- stage xb for BOTH bt (bf16) + nwT ----
    const float4* xg = (const float4*)(x + (size_t)bt0 * NB * FINN);
    #pragma unroll
    for (int itr = 0; itr < 16; ++itr) {
        int idx4 = itr * 256 + tid;     // 0..4095 float4s (2 bt contiguous)
        float4 v = xg[idx4];
        int b = idx4 >> 11;
        int w = idx4 & 2047;
        int j = w >> 3, f = (w & 7) * 4;
        uint2 p;
        p.x = (unsigned)f2bf(v.x) | ((unsigned)f2bf(v.y) << 16);
        p.y = (unsigned)f2bf(v.z) | ((unsigned)f2bf(v.w) << 16);
        *(uint2*)&xb[b][j][f] = p;
    }
    {
        float4 v = ((const float4*)node_w)[tid];
        int f = tid >> 3, o = (tid & 7) * 4;
        nwT[o + 0][f] = f2bf(v.x); nwT[o + 1][f] = f2bf(v.y);
        nwT[o + 2][f] = f2bf(v.z); nwT[o + 3][f] = f2bf(v.w);
    }
    __syncthreads();

    {   // S partials, both bt
        int f = tid & 31, grp = tid >> 5;
        float s0 = 0.f, s1 = 0.f;
        for (int j = grp * 32; j < grp * 32 + 32; ++j) {
            s0 += bf2f(xb[0][j][f]);
            s1 += bf2f(xb[1][j][f]);
        }
        Sp[0][grp][f] = s0;
        Sp[1][grp][f] = s1;
    }

    // production A-frags: wave's 4 j-tiles, both bt
    short8 afr[2][4];
    #pragma unroll
    for (int t = 0; t < 4; ++t) {
        afr[0][t] = *(short8*)&xb[0][(wv * 4 + t) * 16 + m][quad * 8];
        afr[1][t] = *(short8*)&xb[1][(wv * 4 + t) * 16 + m][quad * 8];
    }

    __syncthreads();
    if (tid < 64) {                     // Sv: wave 0 only (b = tid>>5)
        int b = tid >> 5, f = tid & 31;
        float s = 0.f;
        #pragma unroll
        for (int g = 0; g < 8; ++g) s += Sp[b][g][f];
        Sv[b][f] = s;
    }

    floatx4 acc[2][2] = {};             // [bt][o-tile]

    // produce chunk for both bt into Bs[.][buf]
    #define PRODUCE(buf, w)                                                   \
    {                                                                         \
        _Pragma("unroll")                                                     \
        for (int b = 0; b < 2; ++b) {                                         \
            _Pragma("unroll")                                                 \
            for (int t = 0; t < 4; ++t) {                                     \
                floatx4 z = {0.f, 0.f, 0.f, 0.f};                             \
                floatx4 d0 = MFMA16(afr[b][t], w[0], z);                      \
                floatx4 d1 = MFMA16(afr[b][t], w[1], z);                      \
                int col = (wv * 4 + t) * 16 + quad * 4;                       \
                uint2 p0, p1;                                                 \
                p0.x = (unsigned)f2bf(d0[0]) | ((unsigned)f2bf(d0[1]) << 16); \
                p0.y = (unsigned)f2bf(d0[2]) | ((unsigned)f2bf(d0[3]) << 16); \
                p1.x = (unsigned)f2bf(d1[0]) | ((unsigned)f2bf(d1[1]) << 16); \
                p1.y = (unsigned)f2bf(d1[2]) | ((unsigned)f2bf(d1[3]) << 16); \
                *(uint2*)&Bs[b][buf][     m][col] = p0;                       \
                *(uint2*)&Bs[b][buf][16 + m][col] = p1;                       \
            }                                                                 \
        }                                                                     \
    }
    #define GEMMC(buf, ar)                                                    \
    {                                                                         \
        _Pragma("unroll")                                                     \
        for (int kk = 0; kk < 8; ++kk) {                                      \
            _Pragma("unroll")                                                 \
            for (int b = 0; b < 2; ++b) {                                     \
                short8 b0 = *(short8*)&Bs[b][buf][     m][kk * 32 + quad * 8];\
                short8 b1 = *(short8*)&Bs[b][buf][16 + m][kk * 32 + quad * 8];\
                acc[b][0] = MFMA16(ar[kk], b0, acc[b][0]);                    \
                acc[b][1] = MFMA16(ar[kk], b1, acc[b][1]);                    \
            }                                                                 \
        }                                                                     \
    }

    #pragma unroll
    for (int c = 0; c < NCH; ++c) {
        ALOAD(areg[c & 1], c);                        // consumed window c+1
        if (c < NCH - 1) WLOADB(wreg[(c + 1) & 1], c + 1);
        PRODUCE(c & 1, wreg[c & 1]);                  // w-frags from window c-1
        if (c > 0) {
            GEMMC((c - 1) & 1, areg[(c - 1) & 1]);
        } else if (tid < 64) {                        // bias2, wave 0 slack
            int b = tid >> 5, o = tid & 31;
            float bb = node_b[o];
            #pragma unroll
            for (int f = 0; f < FINN; ++f) bb += Sv[b][f] * b2[f * FOUTN + o];
            bias2[b][o] = bb;
        }
        BARRIER();                                    // no vmcnt(0) drain
    }
    GEMMC((NCH - 1) & 1, areg[(NCH - 1) & 1]);        // final window

    // ---- epilogue: + x@node_w (1 MFMA/tile) + bias2, gelu, store ----
    #pragma unroll
    for (int b = 0; b < 2; ++b) {
        short8 xa = *(short8*)&xb[b][i0g + m][quad * 8];
        #pragma unroll
        for (int tn = 0; tn < 2; ++tn) {
            short8 nb = *(short8*)&nwT[tn * 16 + m][quad * 8];
            acc[b][tn] = MFMA16(xa, nb, acc[b][tn]);
        }
        #pragma unroll
        for (int tn = 0; tn < 2; ++tn) {
            int o = tn * 16 + m;
            float bz = bias2[b][o];
            #pragma unroll
            for (int r = 0; r < 4; ++r) {
                int row = i0g + quad * 4 + r;
                out[((size_t)(bt0 + b) * NB + row) * FOUTN + o] =
                    gelu_f(acc[b][tn][r] + bz);
            }
        }
    }
}

// ---------------------------------------------------------------------------
extern "C" void kernel_launch(void* const* d_in, const int* in_sizes, int n_in,
                              void* d_out, int out_size, void* d_ws, size_t ws_size,
                              hipStream_t stream) {
    const float* x      = (const float*)d_in[0];
    const float* adj    = (const float*)d_in[1];
    const float* w1     = (const float*)d_in[2];
    const float* b1     = (const float*)d_in[3];
    const float* w2     = (const float*)d_in[4];
    const float* b2     = (const float*)d_in[5];
    const float* node_w = (const float*)d_in[6];
    const float* node_b = (const float*)d_in[7];
    float* out = (float*)d_out;

    ushort* Hf  = (ushort*)d_ws;                 // 2 MiB, A-fragment order
    ushort* w2f = Hf + (size_t)NB * KKD;         // 32 KiB, B-fragment order

    hipLaunchKernelGGL(h_kernel, dim3(129), dim3(256), 0, stream,
                       adj, w1, b1, w2, Hf, w2f);
    hipLaunchKernelGGL(fused_kernel, dim3(BT / 2, 4), dim3(256), 0, stream,
                       x, w2f, b2, node_w, node_b, Hf, out);
}

// Round 12
// 94.955 us; speedup vs baseline: 1.0674x; 1.0674x over previous
//
#include <hip/hip_runtime.h>
#include <math.h>

// Problem constants
#define NB    256           // N nodes
#define EDIM  16            // edge MLP hidden
#define FINN  32            // Fin
#define FOUTN 32            // Fout
#define BT    128           // B*T
#define KKD   4096          // GEMM K index: e*256 + j

typedef __attribute__((ext_vector_type(8))) short short8;   // 8 bf16 = 4 VGPRs
typedef __attribute__((ext_vector_type(4))) float floatx4;  // MFMA accumulator

#define MFMA16(a,b,c) __builtin_amdgcn_mfma_f32_16x16x32_bf16((a),(b),(c),0,0,0)

// Raw barrier: LDS ordering only — DOES NOT drain in-flight global register
// loads (vs __syncthreads' s_waitcnt vmcnt(0), the m97 structural stall).
// Safe here: Bs producer->consumer needs only lgkmcnt; A/W loads are
// wave-private and wait at their use site.
#define BARRIER() asm volatile("s_waitcnt lgkmcnt(0)\n\ts_barrier" ::: "memory")

__device__ __forceinline__ float gelu_f(float v) {
    return 0.5f * v * (1.0f + erff(v * 0.70710678118654752f));
}
__device__ __forceinline__ ushort f2bf(float x) {
    union { float f; unsigned u; } v; v.f = x;
    unsigned r = (v.u + 0x7FFFu + ((v.u >> 16) & 1u)) >> 16;
    return (ushort)r;
}
__device__ __forceinline__ float bf2f(ushort b) {
    union { unsigned u; float f; } v; v.u = ((unsigned)b) << 16; return v.f;
}

// ---------------------------------------------------------------------------
// Prep: blocks [0,128): H in MFMA A-fragment order.
//       block 128:      w2 -> bf16 in MFMA B-fragment order.
// ---------------------------------------------------------------------------
__global__ __launch_bounds__(256) void h_kernel(const float* __restrict__ adj,
                                                const float* __restrict__ w1,
                                                const float* __restrict__ b1,
                                                const float* __restrict__ w2,
                                                ushort* __restrict__ Hf,
                                                ushort* __restrict__ w2f) {
    int tid = threadIdx.x;
    if (blockIdx.x >= 128) {
        for (int s = 0; s < 2048; s += 256) {
            int slot = s + tid;             // (e*2+ot)*64 + lane
            int e = slot >> 7, r = slot & 127;
            int ot = r >> 6, lane = r & 63;
            int m = lane & 15, quad = lane >> 4;
            const float* src = w2 + (size_t)e * 1024 + (quad * 8) * 32 + ot * 16 + m;
            ushort tmp[8];
            #pragma unroll
            for (int i = 0; i < 8; ++i) tmp[i] = f2bf(src[i * 32]);
            *(int4*)(w2f + (size_t)slot * 8) = *(int4*)tmp;
        }
        return;
    }
    __shared__ float adjs[16][264];
    __shared__ float w1s[16], b1s[16];
    int it = blockIdx.x & 15;
    int kq = blockIdx.x >> 4;               // 0..7
    if (tid < 16) { w1s[tid] = w1[tid]; b1s[tid] = b1[tid]; }
    #pragma unroll
    for (int q = 0; q < 4; ++q) {
        int u = q * 256 + tid;
        int row = u >> 6, c4 = u & 63;
        *(float4*)&adjs[row][c4 * 4] =
            ((const float4*)(adj + ((size_t)it * 16 + row) * 256))[c4];
    }
    __syncthreads();
    #pragma unroll
    for (int q = 0; q < 4; ++q) {
        int u = q * 256 + tid;              // 16 ks x 64 lanes
        int ks = kq * 16 + (u >> 6);
        int lane = u & 63;
        int m = lane & 15, quad = lane >> 4;
        int e = ks >> 3;
        int j0 = (ks & 7) * 32 + quad * 8;
        float w = w1s[e], b = b1s[e];
        ushort tmp[8];
        #pragma unroll
        for (int d = 0; d < 8; ++d)
            tmp[d] = f2bf(gelu_f(adjs[m][j0 + d] * w + b));
        *(int4*)(Hf + (((size_t)it * 128 + ks) * 64 + lane) * 8) = *(int4*)tmp;
    }
}

// ---------------------------------------------------------------------------
// Fused y2 + GEMM + epilogue (best measured config: R8 structure + drain-free
// K-loop barriers). Block = (bt, iq); 256 thr = 4 waves; grid 512;
// LDS ~58 KB -> 2 blocks/CU. Window c: ALOAD(c) + WLOADB(c+1) fired first
// (consumed next window, NOT drained at barriers); PRODUCE(c); GEMM(c-1);
// raw lgkmcnt barrier.
// ---------------------------------------------------------------------------
#define NCH  16
#define BSP  264   // Bs padded row (bf16)
#define XBP  40    // xb/nwT padded row (bf16)

__global__ __launch_bounds__(256, 2) void fused_kernel(
        const float* __restrict__ x,      const ushort* __restrict__ w2f,
        const float* __restrict__ b2,     const float* __restrict__ node_w,
        const float* __restrict__ node_b, const ushort* __restrict__ Hf,
        float* __restrict__ out) {
    __shared__ ushort xb[NB][XBP];      // 20 KiB   x[bt] in bf16
    __shared__ ushort Bs[2][32][BSP];   // 33 KiB   y2 chunk dbuf [o][j]
    __shared__ ushort nwT[32][XBP];     // 2.5 KiB  node_w^T in bf16
    __shared__ float  Sp[8][32];
    __shared__ float  Sv[32];
    __shared__ float  bias2[32];

    int bt   = blockIdx.x;              // 0..127
    int iq   = blockIdx.y;              // 0..3
    int tid  = threadIdx.x;
    int wv   = tid >> 6;                // 0..3
    int lane = tid & 63;
    int m    = lane & 15;
    int quad = lane >> 4;
    int it   = iq * 4 + wv;             // wave's i-tile (16 rows)
    int i0g  = it * 16;

    const ushort* Hlane = Hf + (size_t)it * 128 * 512 + lane * 8;
    const ushort* Wlane = w2f + (size_t)lane * 8;

    short8 areg[2][8];                  // A-frag ping-pong
    short8 wreg[2][2];                  // w2-frag ping-pong (both o-halves)

    #define ALOAD(dst, c)                                                     \
    {                                                                         \
        _Pragma("unroll")                                                     \
        for (int kk = 0; kk < 8; ++kk)                                        \
            dst[kk] = *(const short8*)(Hlane + ((c) * 8 + kk) * 512);         \
    }
    #define WLOADB(dst, e)                                                    \
    {                                                                         \
        dst[0] = *(const short8*)(Wlane + (size_t)(e) * 1024);                \
        dst[1] = *(const short8*)(Wlane + (size_t)(e) * 1024 + 512);          \
    }

    WLOADB(wreg[0], 0);                 // chunk-0 w2 frags (used after staging)

    // ---- stage xb (bf16) + nwT ----
    const float4* xg = (const float4*)(x + (size_t)bt * NB * FINN);
    #pragma unroll
    for (int itr = 0; itr < 8; ++itr) {
        int idx4 = itr * 256 + tid;
        float4 v = xg[idx4];
        int j = idx4 >> 3, f = (idx4 & 7) * 4;
        uint2 p;
        p.x = (unsigned)f2bf(v.x) | ((unsigned)f2bf(v.y) << 16);
        p.y = (unsigned)f2bf(v.z) | ((unsigned)f2bf(v.w) << 16);
        *(uint2*)&xb[j][f] = p;
    }
    {
        float4 v = ((const float4*)node_w)[tid];
        int f = tid >> 3, o = (tid & 7) * 4;
        nwT[o + 0][f] = f2bf(v.x); nwT[o + 1][f] = f2bf(v.y);
        nwT[o + 2][f] = f2bf(v.z); nwT[o + 3][f] = f2bf(v.w);
    }
    __syncthreads();

    {   // S partials
        int f = tid & 31, grp = tid >> 5;
        float s = 0.f;
        for (int j = grp * 32; j < grp * 32 + 32; ++j) s += bf2f(xb[j][f]);
        Sp[grp][f] = s;
    }

    // production A-frags: wave's 4 j-tiles
    short8 afr[4];
    #pragma unroll
    for (int t = 0; t < 4; ++t)
        afr[t] = *(short8*)&xb[(wv * 4 + t) * 16 + m][quad * 8];

    __syncthreads();
    if (tid < 32) {                     // Sv: written+read by wave 0 only
        float s = 0.f;
        #pragma unroll
        for (int g = 0; g < 8; ++g) s += Sp[g][tid];
        Sv[tid] = s;
    }

    floatx4 acc[2] = {};

    // produce chunk into Bs[buf]: D[j][o] contiguous 4-j runs per lane
    #define PRODUCE(buf, w)                                                   \
    {                                                                         \
        _Pragma("unroll")                                                     \
        for (int t = 0; t < 4; ++t) {                                         \
            floatx4 z = {0.f, 0.f, 0.f, 0.f};                                 \
            floatx4 d0 = MFMA16(afr[t], w[0], z);                             \
            floatx4 d1 = MFMA16(afr[t], w[1], z);                             \
            int col = (wv * 4 + t) * 16 + quad * 4;                           \
            uint2 p0, p1;                                                     \
            p0.x = (unsigned)f2bf(d0[0]) | ((unsigned)f2bf(d0[1]) << 16);     \
            p0.y = (unsigned)f2bf(d0[2]) | ((unsigned)f2bf(d0[3]) << 16);     \
            p1.x = (unsigned)f2bf(d1[0]) | ((unsigned)f2bf(d1[1]) << 16);     \
            p1.y = (unsigned)f2bf(d1[2]) | ((unsigned)f2bf(d1[3]) << 16);     \
            *(uint2*)&Bs[buf][     m][col] = p0;                              \
            *(uint2*)&Bs[buf][16 + m][col] = p1;                              \
        }                                                                     \
    }
    #define GEMMC(buf, ar)                                                    \
    {                                                                         \
        _Pragma("unroll")                                                     \
        for (int kk = 0; kk < 8; ++kk) {                                      \
            short8 b0 = *(short8*)&Bs[buf][     m][kk * 32 + quad * 8];       \
            short8 b1 = *(short8*)&Bs[buf][16 + m][kk * 32 + quad * 8];       \
            acc[0] = MFMA16(ar[kk], b0, acc[0]);                              \
            acc[1] = MFMA16(ar[kk], b1, acc[1]);                              \
        }                                                                     \
    }

    #pragma unroll
    for (int c = 0; c < NCH; ++c) {
        ALOAD(areg[c & 1], c);                        // consumed window c+1
        if (c < NCH - 1) WLOADB(wreg[(c + 1) & 1], c + 1);
        PRODUCE(c & 1, wreg[c & 1]);                  // w-frags from window c-1
        if (c > 0) {
            GEMMC((c - 1) & 1, areg[(c - 1) & 1]);
        } else if (tid < 32) {                        // slack in window 0
            float bb = node_b[tid];
            #pragma unroll
            for (int f = 0; f < FINN; ++f) bb += Sv[f] * b2[f * FOUTN + tid];
            bias2[tid] = bb;
        }
        BARRIER();                                    // no vmcnt(0) drain
    }
    GEMMC((NCH - 1) & 1, areg[(NCH - 1) & 1]);        // final window

    // ---- epilogue: + x@node_w (1 MFMA/tile) + bias2, gelu, store ----
    {
        short8 xa = *(short8*)&xb[i0g + m][quad * 8];
        #pragma unroll
        for (int tn = 0; tn < 2; ++tn) {
            short8 nb = *(short8*)&nwT[tn * 16 + m][quad * 8];
            acc[tn] = MFMA16(xa, nb, acc[tn]);
        }
    }
    #pragma unroll
    for (int tn = 0; tn < 2; ++tn) {
        int o = tn * 16 + m;
        float bz = bias2[o];
        #pragma unroll
        for (int r = 0; r < 4; ++r) {
            int row = i0g + quad * 4 + r;
            out[((size_t)bt * NB + row) * FOUTN + o] = gelu_f(acc[tn][r] + bz);
        }
    }
}

// ---------------------------------------------------------------------------
extern "C" void kernel_launch(void* const* d_in, const int* in_sizes, int n_in,
                              void* d_out, int out_size, void* d_ws, size_t ws_size,
                              hipStream_t stream) {
    const float* x      = (const float*)d_in[0];
    const float* adj    = (const float*)d_in[1];
    const float* w1     = (const float*)d_in[2];
    const float* b1     = (const float*)d_in[3];
    const float* w2     = (const float*)d_in[4];
    const float* b2     = (const float*)d_in[5];
    const float* node_w = (const float*)d_in[6];
    const float* node_b = (const float*)d_in[7];
    float* out = (float*)d_out;

    ushort* Hf  = (ushort*)d_ws;                 // 2 MiB, A-fragment order
    ushort* w2f = Hf + (size_t)NB * KKD;         // 32 KiB, B-fragment order

    hipLaunchKernelGGL(h_kernel, dim3(129), dim3(256), 0, stream,
                       adj, w1, b1, w2, Hf, w2f);
    hipLaunchKernelGGL(fused_kernel, dim3(BT, 4), dim3(256), 0, stream,
                       x, w2f, b2, node_w, node_b, Hf, out);
}